// Round 6
// baseline (590.379 us; speedup 1.0000x reference)
//
#include <hip/hip_runtime.h>
#include <cstdint>

// SpacetimeNonLocalBlock: B=4, C=256, T*H*W=N=6272, IC=128.
// R5: LDS-bandwidth round. flash3: 64 q per wave (2x reuse per A-operand read),
// TK=32, KSPL=4, 4-bit K swizzle (2-way=free), stride-36 V (conflict-free b64),
// exp2-domain softmax (Q pre-scaled by log2e), wave-uniform skip of accO
// rescale. proj/zres: transposed-LDS b128 versions (R3's, verified innocent —
// R3's real bug was the Lpart offset in kernel_launch, fixed in R4/here).
// ws: Qg|Kg|Vtg f16 | Opart f16 KSPL*BNIC | Mpart,Lpart f32 KSPL*B*N = ~46 MB.

#define BB   4
#define CCH  256
#define NPOS 6272
#define ICH  128
#define BNIC ((size_t)BB * NPOS * ICH)
#define KSPL 4
#define KLEN (NPOS / KSPL)   // 1568
#define TKF  32
#define NITK (KLEN / TKF)    // 49
#define QPB  256             // q per block (4 waves x 64 q)
#define NQB  25              // ceil(6272/256) -> last block padded/guarded

typedef __attribute__((ext_vector_type(8)))  _Float16 h8v;  // 8 f16 MFMA frag
typedef __attribute__((ext_vector_type(16))) float fx16;    // 32x32 acc

__device__ __forceinline__ unsigned short f2h(float f) {
  _Float16 h = (_Float16)f;
  return __builtin_bit_cast(unsigned short, h);
}
__device__ __forceinline__ unsigned int pkh(float lo, float hi) {
  return __builtin_bit_cast(unsigned int, __builtin_amdgcn_cvt_pkrtz(lo, hi));
}

// ---------------------------------------------------------------------------
// proj_qk: Q/K [b][n][128] f16; Q pre-scaled by log2(e) (exp2-domain softmax).
// LDS transposed [k][n] -> b128 inner reads.
// ---------------------------------------------------------------------------
__global__ __launch_bounds__(256, 2)
void proj_qk(const float* __restrict__ x,
             const float* __restrict__ Wtheta,
             const float* __restrict__ Wphi,
             unsigned short* __restrict__ Qg,
             unsigned short* __restrict__ Kg) {
  const int n0 = blockIdx.x * 64;
  const int p  = blockIdx.y >> 1;
  const int o_half = (blockIdx.y & 1) * 64;
  const int b  = blockIdx.z;
  const float* W = p ? Wphi : Wtheta;
  unsigned short* Out = p ? Kg : Qg;
  const float scl = p ? 1.0f : 1.4426950408889634f;

  __shared__ float Xt[16][68];   // [k][n]
  __shared__ float Wt[16][68];   // [k][o]
  const int tid = threadIdx.x;
  const int tx = tid & 15, ty = tid >> 4;
  float acc[4][4] = {};          // rows n = ty*4+i, cols o = tx*4+j

  for (int c0 = 0; c0 < CCH; c0 += 16) {
    {
      const int nn = tid & 63, k4 = tid >> 6;
      #pragma unroll
      for (int q = 0; q < 4; ++q) {
        const int kk = k4 + q * 4;
        Xt[kk][nn] = x[((size_t)(b * CCH + c0 + kk)) * NPOS + n0 + nn];
      }
      const int wk = tid & 15, wo = tid >> 4;
      #pragma unroll
      for (int q = 0; q < 4; ++q) {
        const int oo = wo + q * 16;
        Wt[wk][oo] = W[(size_t)(o_half + oo) * CCH + c0 + wk];
      }
    }
    __syncthreads();
    #pragma unroll
    for (int kk = 0; kk < 16; ++kk) {
      const float4 av = *(const float4*)&Xt[kk][ty * 4];
      const float4 bv = *(const float4*)&Wt[kk][tx * 4];
      const float a_[4] = {av.x, av.y, av.z, av.w};
      const float b_[4] = {bv.x, bv.y, bv.z, bv.w};
      #pragma unroll
      for (int i = 0; i < 4; ++i)
        #pragma unroll
        for (int j = 0; j < 4; ++j) acc[i][j] += a_[i] * b_[j];
    }
    __syncthreads();
  }
  #pragma unroll
  for (int i = 0; i < 4; ++i) {
    ushort4 v;
    v.x = f2h(acc[i][0] * scl); v.y = f2h(acc[i][1] * scl);
    v.z = f2h(acc[i][2] * scl); v.w = f2h(acc[i][3] * scl);
    *(ushort4*)&Out[((size_t)b * NPOS + n0 + ty * 4 + i) * ICH + o_half + tx * 4] = v;
  }
}

// ---------------------------------------------------------------------------
// proj_v: V^T [b][128][N] f16.
// ---------------------------------------------------------------------------
__global__ __launch_bounds__(256, 2)
void proj_v(const float* __restrict__ x,
            const float* __restrict__ Wg,
            unsigned short* __restrict__ Vtg) {
  const int n0 = blockIdx.x * 64;
  const int o_half = blockIdx.y * 64;
  const int b  = blockIdx.z;
  __shared__ float Xt[16][68];
  __shared__ float Wt[16][68];
  const int tid = threadIdx.x;
  const int tx = tid & 15, ty = tid >> 4;
  float acc[4][4] = {};          // rows o = ty*4+i, cols n = tx*4+j

  for (int c0 = 0; c0 < CCH; c0 += 16) {
    {
      const int nn = tid & 63, k4 = tid >> 6;
      #pragma unroll
      for (int q = 0; q < 4; ++q) {
        const int kk = k4 + q * 4;
        Xt[kk][nn] = x[((size_t)(b * CCH + c0 + kk)) * NPOS + n0 + nn];
      }
      const int wk = tid & 15, wo = tid >> 4;
      #pragma unroll
      for (int q = 0; q < 4; ++q) {
        const int oo = wo + q * 16;
        Wt[wk][oo] = Wg[(size_t)(o_half + oo) * CCH + c0 + wk];
      }
    }
    __syncthreads();
    #pragma unroll
    for (int kk = 0; kk < 16; ++kk) {
      const float4 av = *(const float4*)&Wt[kk][ty * 4];
      const float4 bv = *(const float4*)&Xt[kk][tx * 4];
      const float a_[4] = {av.x, av.y, av.z, av.w};
      const float b_[4] = {bv.x, bv.y, bv.z, bv.w};
      #pragma unroll
      for (int i = 0; i < 4; ++i)
        #pragma unroll
        for (int j = 0; j < 4; ++j) acc[i][j] += a_[i] * b_[j];
    }
    __syncthreads();
  }
  #pragma unroll
  for (int i = 0; i < 4; ++i) {
    ushort4 v;
    v.x = f2h(acc[i][0]); v.y = f2h(acc[i][1]);
    v.z = f2h(acc[i][2]); v.w = f2h(acc[i][3]);
    *(ushort4*)&Vtg[((size_t)b * ICH + o_half + ty * 4 + i) * NPOS + n0 + tx * 4] = v;
  }
}

// ---------------------------------------------------------------------------
// flash3: grid (25, KSPL, B), 256 thr = 4 waves; wave w owns q cols
// n0+64w .. +63 (two 32-q subtiles q2). TK=32. Emits unnorm f16 Opart + (m,l)
// in log2 domain. LDS 34 KB: Ks[2][32x128] (4-bit swz), Vs[2][128x36].
// ---------------------------------------------------------------------------
__global__ __launch_bounds__(256, 1)
void flash3(const unsigned short* __restrict__ Qg,
            const unsigned short* __restrict__ Kg,
            const unsigned short* __restrict__ Vtg,
            unsigned short* __restrict__ Opart,
            float* __restrict__ Mpart,
            float* __restrict__ Lpart) {
  __shared__ unsigned short Ks[2][TKF * 128];   // row kr: 16 chunks, pos = c^(kr&15)
  __shared__ unsigned short Vs[2][128 * 36];    // row dr: stride 36 el (72 B)

  const int b   = blockIdx.z;
  const int spl = blockIdx.y;
  const int n0  = blockIdx.x * QPB;
  const int kb  = spl * KLEN;
  const int tid = threadIdx.x;
  const int lane = tid & 63, wv = tid >> 6;
  const int qlane = lane & 31, g = lane >> 5;
  const int swz = qlane & 15;

  // Q fragments in registers (B-operand), 2 q-subtiles per wave, clamped rows
  h8v qf[2][8];
  #pragma unroll
  for (int q2 = 0; q2 < 2; ++q2) {
    int row = n0 + 64 * wv + 32 * q2 + qlane;
    if (row >= NPOS) row = NPOS - 1;
    const size_t qbase = ((size_t)b * NPOS + row) * ICH;
    #pragma unroll
    for (int cs = 0; cs < 8; ++cs)
      qf[q2][cs] = *(const h8v*)&Qg[qbase + cs * 16 + g * 8];
  }

  // prologue: tile 0 -> buffer 0
  {
    #pragma unroll
    for (int i = 0; i < 2; ++i) {
      const int kr = (tid >> 4) + i * 16, c = tid & 15;
      const uint4 v = *(const uint4*)&Kg[((size_t)b * NPOS + kb + kr) * ICH + c * 8];
      *(uint4*)&Ks[0][kr * 128 + (c ^ (kr & 15)) * 8] = v;
      const int idx = tid * 2 + i, dr = idx >> 2, cv = idx & 3;
      const uint4 w = *(const uint4*)&Vtg[((size_t)b * ICH + dr) * NPOS + kb + cv * 8];
      *(uint2*)&Vs[0][dr * 36 + cv * 8]     = make_uint2(w.x, w.y);
      *(uint2*)&Vs[0][dr * 36 + cv * 8 + 4] = make_uint2(w.z, w.w);
    }
  }
  __syncthreads();

  float m_run[2] = {-1e30f, -1e30f}, l_run[2] = {0.0f, 0.0f};
  fx16 accO[2][4];
  #pragma unroll
  for (int q2 = 0; q2 < 2; ++q2)
    #pragma unroll
    for (int mt = 0; mt < 4; ++mt) accO[q2][mt] = (fx16)(0.0f);

  uint4 stgK[2], stgV[2];

  for (int it = 0; it < NITK; ++it) {
    const int cur = it & 1;
    const bool pre = (it + 1 < NITK);
    if (pre) {  // global prefetch for next tile; commit deferred past compute
      const int k0n = kb + (it + 1) * TKF;
      #pragma unroll
      for (int i = 0; i < 2; ++i) {
        const int kr = (tid >> 4) + i * 16;
        stgK[i] = *(const uint4*)&Kg[((size_t)b * NPOS + k0n + kr) * ICH + (tid & 15) * 8];
        const int idx = tid * 2 + i, dr = idx >> 2, cv = idx & 3;
        stgV[i] = *(const uint4*)&Vtg[((size_t)b * ICH + dr) * NPOS + k0n + cv * 8];
      }
    }

    // ---- S^T = K . Q^T : D[k=32][q=32] x 2 q-subtiles (aK reused) ----
    fx16 accS[2];
    accS[0] = (fx16)(0.0f); accS[1] = (fx16)(0.0f);
    #pragma unroll
    for (int cs = 0; cs < 8; ++cs) {
      const h8v aK = *(const h8v*)&Ks[cur][qlane * 128 + ((2 * cs + g) ^ swz) * 8];
      accS[0] = __builtin_amdgcn_mfma_f32_32x32x16_f16(aK, qf[0][cs], accS[0], 0, 0, 0);
      accS[1] = __builtin_amdgcn_mfma_f32_32x32x16_f16(aK, qf[1][cs], accS[1], 0, 0, 0);
    }

    // ---- online softmax, log2 domain (Q pre-scaled by log2e) ----
    float mn[2], lsum[2];
    unsigned int pk[2][4][2];
    bool up = false;
    #pragma unroll
    for (int q2 = 0; q2 < 2; ++q2) {
      float mx = accS[q2][0];
      #pragma unroll
      for (int r = 1; r < 16; ++r) mx = fmaxf(mx, accS[q2][r]);
      mx = fmaxf(mx, __shfl_xor(mx, 32));
      up = up || (mx > m_run[q2]);
      mn[q2] = fmaxf(m_run[q2], mx);
      float ls = 0.0f;
      #pragma unroll
      for (int u = 0; u < 4; ++u) {
        const float p0 = exp2f(accS[q2][4 * u + 0] - mn[q2]);
        const float p1 = exp2f(accS[q2][4 * u + 1] - mn[q2]);
        const float p2 = exp2f(accS[q2][4 * u + 2] - mn[q2]);
        const float p3 = exp2f(accS[q2][4 * u + 3] - mn[q2]);
        ls += (p0 + p1) + (p2 + p3);
        pk[q2][u][0] = pkh(p0, p1);
        pk[q2][u][1] = pkh(p2, p3);
      }
      ls += __shfl_xor(ls, 32);
      lsum[q2] = ls;
    }
    if (__any(up)) {  // rescale only when some lane's max advanced
      #pragma unroll
      for (int q2 = 0; q2 < 2; ++q2) {
        const float alpha = exp2f(m_run[q2] - mn[q2]);
        l_run[q2] = l_run[q2] * alpha + lsum[q2];
        m_run[q2] = mn[q2];
        #pragma unroll
        for (int mt = 0; mt < 4; ++mt)
          #pragma unroll
          for (int r = 0; r < 16; ++r) accO[q2][mt][r] *= alpha;
      }
    } else {
      l_run[0] += lsum[0];
      l_run[1] += lsum[1];
    }

    // ---- PV: O^T += V^T . P^T (aV reused across q2) ----
    #pragma unroll
    for (int s = 0; s < 2; ++s) {
      union { unsigned int u[4]; h8v v; } bP[2];
      #pragma unroll
      for (int q2 = 0; q2 < 2; ++q2) {
        const unsigned int s0 = pk[q2][2 * s + (g ^ 1)][0];
        const unsigned int s1 = pk[q2][2 * s + (g ^ 1)][1];
        const unsigned int t0 = __shfl_xor(s0, 32);
        const unsigned int t1 = __shfl_xor(s1, 32);
        bP[q2].u[0] = g ? t0 : pk[q2][2 * s][0];
        bP[q2].u[1] = g ? t1 : pk[q2][2 * s][1];
        bP[q2].u[2] = g ? pk[q2][2 * s + 1][0] : t0;
        bP[q2].u[3] = g ? pk[q2][2 * s + 1][1] : t1;
      }
      #pragma unroll
      for (int mt = 0; mt < 4; ++mt) {
        const int dr = 32 * mt + qlane;
        union { unsigned int u[4]; h8v v; } aV;
        const uint2 lo = *(const uint2*)&Vs[cur][dr * 36 + (2 * s + g) * 8];
        const uint2 hi = *(const uint2*)&Vs[cur][dr * 36 + (2 * s + g) * 8 + 4];
        aV.u[0] = lo.x; aV.u[1] = lo.y; aV.u[2] = hi.x; aV.u[3] = hi.y;
        accO[0][mt] = __builtin_amdgcn_mfma_f32_32x32x16_f16(aV.v, bP[0].v, accO[0][mt], 0, 0, 0);
        accO[1][mt] = __builtin_amdgcn_mfma_f32_32x32x16_f16(aV.v, bP[1].v, accO[1][mt], 0, 0, 0);
      }
    }

    if (pre) {  // commit staged tile to the other buffer
      const int nb = cur ^ 1;
      #pragma unroll
      for (int i = 0; i < 2; ++i) {
        const int kr = (tid >> 4) + i * 16;
        *(uint4*)&Ks[nb][kr * 128 + ((tid & 15) ^ (kr & 15)) * 8] = stgK[i];
        const int idx = tid * 2 + i, dr = idx >> 2, cv = idx & 3;
        *(uint2*)&Vs[nb][dr * 36 + cv * 8]     = make_uint2(stgV[i].x, stgV[i].y);
        *(uint2*)&Vs[nb][dr * 36 + cv * 8 + 4] = make_uint2(stgV[i].z, stgV[i].w);
      }
    }
    __syncthreads();
  }

  // epilogue: unnormalized f16 partial O + per-column (m,l), guarded vs pad
  const size_t obase = (size_t)(b * KSPL + spl) * ICH * NPOS;
  #pragma unroll
  for (int q2 = 0; q2 < 2; ++q2) {
    const int ncol = n0 + 64 * wv + 32 * q2 + qlane;
    if (ncol < NPOS) {
      #pragma unroll
      for (int mt = 0; mt < 4; ++mt)
        #pragma unroll
        for (int r = 0; r < 16; ++r) {
          const int d = 32 * mt + (r & 3) + 8 * (r >> 2) + 4 * g;
          Opart[obase + (size_t)d * NPOS + ncol] = f2h(accO[q2][mt][r]);
        }
      if (g == 0) {
        Mpart[(size_t)(b * KSPL + spl) * NPOS + ncol] = m_run[q2];
        Lpart[(size_t)(b * KSPL + spl) * NPOS + ncol] = l_run[q2];
      }
    }
  }
}

// ---------------------------------------------------------------------------
// merge: Y^T[b][d][n] = sum_s 2^{m_s-M} O_s[d][n] / sum_s 2^{m_s-M} l_s
// ---------------------------------------------------------------------------
__global__ __launch_bounds__(256, 2)
void merge_kernel(const unsigned short* __restrict__ Opart,
                  const float* __restrict__ Mpart,
                  const float* __restrict__ Lpart,
                  float* __restrict__ Yt) {
  const int idx = blockIdx.x * 256 + threadIdx.x;   // 0 .. B*N-1
  const int b = idx / NPOS, n = idx % NPOS;
  float m[KSPL], l[KSPL], M = -1e30f;
  #pragma unroll
  for (int s = 0; s < KSPL; ++s) {
    m[s] = Mpart[(size_t)(b * KSPL + s) * NPOS + n];
    l[s] = Lpart[(size_t)(b * KSPL + s) * NPOS + n];
    M = fmaxf(M, m[s]);
  }
  float w[KSPL], ltot = 0.0f;
  #pragma unroll
  for (int s = 0; s < KSPL; ++s) { w[s] = exp2f(m[s] - M); ltot += w[s] * l[s]; }
  const float inv = 1.0f / ltot;
  for (int d = 0; d < ICH; ++d) {
    float acc = 0.0f;
    #pragma unroll
    for (int s = 0; s < KSPL; ++s) {
      const unsigned short u = Opart[((size_t)(b * KSPL + s) * ICH + d) * NPOS + n];
      acc += w[s] * (float)__builtin_bit_cast(_Float16, u);
    }
    Yt[((size_t)b * ICH + d) * NPOS + n] = acc * inv;
  }
}

// ---------------------------------------------------------------------------
// zres: out[b][c][n] = sum_ic Wz[c][ic] * Y^T[b][ic][n] + x  (b128 LDS)
// ---------------------------------------------------------------------------
__global__ __launch_bounds__(256, 2)
void zres_kernel(const float* __restrict__ x,
                 const float* __restrict__ Wz,
                 const float* __restrict__ Yt,
                 float* __restrict__ out) {
  const int n0 = blockIdx.x * 64;
  const int c0 = blockIdx.y * 64;
  const int b  = blockIdx.z;
  __shared__ float Yts[16][68];   // [k(ic)][n]
  __shared__ float Wzt[16][68];   // [k][c]
  const int tid = threadIdx.x;
  const int tx = tid & 15, ty = tid >> 4;
  float acc[4][4] = {};           // rows c = ty*4+i, cols n = tx*4+j

  for (int ic0 = 0; ic0 < ICH; ic0 += 16) {
    {
      const int nn = tid & 63, k4 = tid >> 6;
      #pragma unroll
      for (int q = 0; q < 4; ++q) {
        const int kk = k4 + q * 4;
        Yts[kk][nn] = Yt[((size_t)b * ICH + ic0 + kk) * NPOS + n0 + nn];
      }
      const int wk = tid & 15, wo = tid >> 4;
      #pragma unroll
      for (int q = 0; q < 4; ++q) {
        const int cc = wo + q * 16;
        Wzt[wk][cc] = Wz[(size_t)(c0 + cc) * ICH + ic0 + wk];
      }
    }
    __syncthreads();
    #pragma unroll
    for (int kk = 0; kk < 16; ++kk) {
      const float4 av = *(const float4*)&Wzt[kk][ty * 4];
      const float4 bv = *(const float4*)&Yts[kk][tx * 4];
      const float a_[4] = {av.x, av.y, av.z, av.w};
      const float b_[4] = {bv.x, bv.y, bv.z, bv.w};
      #pragma unroll
      for (int i = 0; i < 4; ++i)
        #pragma unroll
        for (int j = 0; j < 4; ++j) acc[i][j] += a_[i] * b_[j];
    }
    __syncthreads();
  }
  #pragma unroll
  for (int i = 0; i < 4; ++i) {
    const size_t base = ((size_t)(b * CCH + c0 + ty * 4 + i)) * NPOS + n0 + tx * 4;
    const float4 xr = *(const float4*)&x[base];
    float4 v;
    v.x = acc[i][0] + xr.x; v.y = acc[i][1] + xr.y;
    v.z = acc[i][2] + xr.z; v.w = acc[i][3] + xr.w;
    *(float4*)&out[base] = v;
  }
}

// ---------------------------------------------------------------------------
extern "C" void kernel_launch(void* const* d_in, const int* in_sizes, int n_in,
                              void* d_out, int out_size, void* d_ws, size_t ws_size,
                              hipStream_t stream) {
  const float* x      = (const float*)d_in[0];
  const float* Wg     = (const float*)d_in[1];
  const float* Wtheta = (const float*)d_in[2];
  const float* Wphi   = (const float*)d_in[3];
  const float* Wz     = (const float*)d_in[4];
  float* out = (float*)d_out;

  unsigned short* Qg    = (unsigned short*)d_ws;
  unsigned short* Kg    = Qg + BNIC;
  unsigned short* Vtg   = Kg + BNIC;
  unsigned short* Opart = Vtg + BNIC;                    // KSPL*BNIC ushorts
  float* Mpart = (float*)(Opart + (size_t)KSPL * BNIC);  // KSPL*B*N floats
  float* Lpart = Mpart + (size_t)KSPL * BB * NPOS;       // KSPL*B*N floats
  float* Yt    = (float*)Qg;                             // overlay after flash3

  proj_qk<<<dim3(NPOS / 64, 4, BB), 256, 0, stream>>>(x, Wtheta, Wphi, Qg, Kg);
  proj_v <<<dim3(NPOS / 64, 2, BB), 256, 0, stream>>>(x, Wg, Vtg);
  flash3 <<<dim3(NQB, KSPL, BB),    256, 0, stream>>>(Qg, Kg, Vtg, Opart, Mpart, Lpart);
  merge_kernel<<<dim3(BB * NPOS / 256), 256, 0, stream>>>(Opart, Mpart, Lpart, Yt);
  zres_kernel<<<dim3(NPOS / 64, CCH / 64, BB), 256, 0, stream>>>(x, Wz, Yt, out);
}

// Round 7
// 410.396 us; speedup vs baseline: 1.4386x; 1.4386x over previous
//
#include <hip/hip_runtime.h>
#include <cstdint>

// SpacetimeNonLocalBlock: B=4, C=256, T*H*W=N=6272, IC=128.
// R6: occupancy round. flash4 = R4's verified skeleton with q=32/wave (NOT
// R5's q=64 that hit the 256-reg clamp), TK=32 -> per-wave regs ~210 total
// (accO 64 + accS 16 acc; qf 32 + staging 16 arch) => 2 waves/SIMD
// (launch_bounds(256,2)), so softmax VALU overlaps LDS/MFMA across waves.
// Keeps R5's verified: 4-bit K swizzle + stride-36 V (conflicts 9.8e6->1.25e6),
// exp2-domain softmax (Q pre-scaled log2e), rescale skip, f16 Opart,
// transposed-LDS b128 proj/zres. Grid (49, KSPL=4, B) = 784 blocks.
// ws: Qg|Kg|Vtg f16 | Opart f16 KSPL*BNIC | Mpart,Lpart f32 = 45.8 MB (proven).

#define BB   4
#define CCH  256
#define NPOS 6272
#define ICH  128
#define BNIC ((size_t)BB * NPOS * ICH)
#define KSPL 4
#define KLEN (NPOS / KSPL)   // 1568
#define TKF  32
#define NITK (KLEN / TKF)    // 49

typedef __attribute__((ext_vector_type(8)))  _Float16 h8v;  // 8 f16 MFMA frag
typedef __attribute__((ext_vector_type(16))) float fx16;    // 32x32 acc

__device__ __forceinline__ unsigned short f2h(float f) {
  _Float16 h = (_Float16)f;
  return __builtin_bit_cast(unsigned short, h);
}
__device__ __forceinline__ unsigned int pkh(float lo, float hi) {
  return __builtin_bit_cast(unsigned int, __builtin_amdgcn_cvt_pkrtz(lo, hi));
}

// ---------------------------------------------------------------------------
// proj_qk: Q/K [b][n][128] f16; Q pre-scaled by log2(e). Transposed-LDS b128.
// ---------------------------------------------------------------------------
__global__ __launch_bounds__(256, 2)
void proj_qk(const float* __restrict__ x,
             const float* __restrict__ Wtheta,
             const float* __restrict__ Wphi,
             unsigned short* __restrict__ Qg,
             unsigned short* __restrict__ Kg) {
  const int n0 = blockIdx.x * 64;
  const int p  = blockIdx.y >> 1;
  const int o_half = (blockIdx.y & 1) * 64;
  const int b  = blockIdx.z;
  const float* W = p ? Wphi : Wtheta;
  unsigned short* Out = p ? Kg : Qg;
  const float scl = p ? 1.0f : 1.4426950408889634f;

  __shared__ float Xt[16][68];   // [k][n]
  __shared__ float Wt[16][68];   // [k][o]
  const int tid = threadIdx.x;
  const int tx = tid & 15, ty = tid >> 4;
  float acc[4][4] = {};          // rows n = ty*4+i, cols o = tx*4+j

  for (int c0 = 0; c0 < CCH; c0 += 16) {
    {
      const int nn = tid & 63, k4 = tid >> 6;
      #pragma unroll
      for (int q = 0; q < 4; ++q) {
        const int kk = k4 + q * 4;
        Xt[kk][nn] = x[((size_t)(b * CCH + c0 + kk)) * NPOS + n0 + nn];
      }
      const int wk = tid & 15, wo = tid >> 4;
      #pragma unroll
      for (int q = 0; q < 4; ++q) {
        const int oo = wo + q * 16;
        Wt[wk][oo] = W[(size_t)(o_half + oo) * CCH + c0 + wk];
      }
    }
    __syncthreads();
    #pragma unroll
    for (int kk = 0; kk < 16; ++kk) {
      const float4 av = *(const float4*)&Xt[kk][ty * 4];
      const float4 bv = *(const float4*)&Wt[kk][tx * 4];
      const float a_[4] = {av.x, av.y, av.z, av.w};
      const float b_[4] = {bv.x, bv.y, bv.z, bv.w};
      #pragma unroll
      for (int i = 0; i < 4; ++i)
        #pragma unroll
        for (int j = 0; j < 4; ++j) acc[i][j] += a_[i] * b_[j];
    }
    __syncthreads();
  }
  #pragma unroll
  for (int i = 0; i < 4; ++i) {
    ushort4 v;
    v.x = f2h(acc[i][0] * scl); v.y = f2h(acc[i][1] * scl);
    v.z = f2h(acc[i][2] * scl); v.w = f2h(acc[i][3] * scl);
    *(ushort4*)&Out[((size_t)b * NPOS + n0 + ty * 4 + i) * ICH + o_half + tx * 4] = v;
  }
}

// ---------------------------------------------------------------------------
// proj_v: V^T [b][128][N] f16.
// ---------------------------------------------------------------------------
__global__ __launch_bounds__(256, 2)
void proj_v(const float* __restrict__ x,
            const float* __restrict__ Wg,
            unsigned short* __restrict__ Vtg) {
  const int n0 = blockIdx.x * 64;
  const int o_half = blockIdx.y * 64;
  const int b  = blockIdx.z;
  __shared__ float Xt[16][68];
  __shared__ float Wt[16][68];
  const int tid = threadIdx.x;
  const int tx = tid & 15, ty = tid >> 4;
  float acc[4][4] = {};          // rows o = ty*4+i, cols n = tx*4+j

  for (int c0 = 0; c0 < CCH; c0 += 16) {
    {
      const int nn = tid & 63, k4 = tid >> 6;
      #pragma unroll
      for (int q = 0; q < 4; ++q) {
        const int kk = k4 + q * 4;
        Xt[kk][nn] = x[((size_t)(b * CCH + c0 + kk)) * NPOS + n0 + nn];
      }
      const int wk = tid & 15, wo = tid >> 4;
      #pragma unroll
      for (int q = 0; q < 4; ++q) {
        const int oo = wo + q * 16;
        Wt[wk][oo] = Wg[(size_t)(o_half + oo) * CCH + c0 + wk];
      }
    }
    __syncthreads();
    #pragma unroll
    for (int kk = 0; kk < 16; ++kk) {
      const float4 av = *(const float4*)&Wt[kk][ty * 4];
      const float4 bv = *(const float4*)&Xt[kk][tx * 4];
      const float a_[4] = {av.x, av.y, av.z, av.w};
      const float b_[4] = {bv.x, bv.y, bv.z, bv.w};
      #pragma unroll
      for (int i = 0; i < 4; ++i)
        #pragma unroll
        for (int j = 0; j < 4; ++j) acc[i][j] += a_[i] * b_[j];
    }
    __syncthreads();
  }
  #pragma unroll
  for (int i = 0; i < 4; ++i) {
    ushort4 v;
    v.x = f2h(acc[i][0]); v.y = f2h(acc[i][1]);
    v.z = f2h(acc[i][2]); v.w = f2h(acc[i][3]);
    *(ushort4*)&Vtg[((size_t)b * ICH + o_half + ty * 4 + i) * NPOS + n0 + tx * 4] = v;
  }
}

// ---------------------------------------------------------------------------
// flash4: grid (49, KSPL, B), 256 thr = 4 waves; wave w owns q cols
// n0+32w..+31 (q=32/wave). TK=32. Emits unnorm f16 Opart + (m,l) log2-domain.
// LDS 34 KB: Ks[2][32x128] (4-bit swz, 2-way=free), Vs[2][128x36] (stride 36).
// ---------------------------------------------------------------------------
__global__ __launch_bounds__(256, 2)
void flash4(const unsigned short* __restrict__ Qg,
            const unsigned short* __restrict__ Kg,
            const unsigned short* __restrict__ Vtg,
            unsigned short* __restrict__ Opart,
            float* __restrict__ Mpart,
            float* __restrict__ Lpart) {
  __shared__ unsigned short Ks[2][TKF * 128];   // row kr: 16 chunks, pos = c^(kr&15)
  __shared__ unsigned short Vs[2][128 * 36];    // row dr: stride 36 el (72 B)

  const int b   = blockIdx.z;
  const int spl = blockIdx.y;
  const int n0  = blockIdx.x * 128;
  const int kb  = spl * KLEN;
  const int tid = threadIdx.x;
  const int lane = tid & 63, wv = tid >> 6;
  const int qlane = lane & 31, g = lane >> 5;
  const int swz = qlane & 15;

  // Q fragments in registers for the whole kernel (B-operand: B[ch][q])
  h8v qf[8];
  {
    const size_t qbase = ((size_t)b * NPOS + n0 + 32 * wv + qlane) * ICH;
    #pragma unroll
    for (int cs = 0; cs < 8; ++cs)
      qf[cs] = *(const h8v*)&Qg[qbase + cs * 16 + g * 8];
  }

  // prologue: tile 0 -> buffer 0
  {
    #pragma unroll
    for (int i = 0; i < 2; ++i) {
      const int kr = (tid >> 4) + i * 16, c = tid & 15;
      const uint4 v = *(const uint4*)&Kg[((size_t)b * NPOS + kb + kr) * ICH + c * 8];
      *(uint4*)&Ks[0][kr * 128 + (c ^ (kr & 15)) * 8] = v;
      const int idx = tid * 2 + i, dr = idx >> 2, cv = idx & 3;
      const uint4 w = *(const uint4*)&Vtg[((size_t)b * ICH + dr) * NPOS + kb + cv * 8];
      *(uint2*)&Vs[0][dr * 36 + cv * 8]     = make_uint2(w.x, w.y);
      *(uint2*)&Vs[0][dr * 36 + cv * 8 + 4] = make_uint2(w.z, w.w);
    }
  }
  __syncthreads();

  float m_run = -1e30f, l_run = 0.0f;
  fx16 accO[4];
  #pragma unroll
  for (int mt = 0; mt < 4; ++mt) accO[mt] = (fx16)(0.0f);

  uint4 stgK[2], stgV[2];

  for (int it = 0; it < NITK; ++it) {
    const int cur = it & 1;
    const bool pre = (it + 1 < NITK);
    if (pre) {  // global prefetch for next tile; commit deferred past compute
      const int k0n = kb + (it + 1) * TKF;
      #pragma unroll
      for (int i = 0; i < 2; ++i) {
        const int kr = (tid >> 4) + i * 16;
        stgK[i] = *(const uint4*)&Kg[((size_t)b * NPOS + k0n + kr) * ICH + (tid & 15) * 8];
        const int idx = tid * 2 + i, dr = idx >> 2, cv = idx & 3;
        stgV[i] = *(const uint4*)&Vtg[((size_t)b * ICH + dr) * NPOS + k0n + cv * 8];
      }
    }

    // ---- S^T = K . Q^T : D[k=32][q=32] ----
    fx16 accS = (fx16)(0.0f);
    #pragma unroll
    for (int cs = 0; cs < 8; ++cs) {
      const h8v aK = *(const h8v*)&Ks[cur][qlane * 128 + ((2 * cs + g) ^ swz) * 8];
      accS = __builtin_amdgcn_mfma_f32_32x32x16_f16(aK, qf[cs], accS, 0, 0, 0);
    }

    // ---- online softmax, log2 domain ----
    float mx = accS[0];
    #pragma unroll
    for (int r = 1; r < 16; ++r) mx = fmaxf(mx, accS[r]);
    mx = fmaxf(mx, __shfl_xor(mx, 32));
    const bool up = (mx > m_run);
    const float mn = fmaxf(m_run, mx);
    float lsum = 0.0f;
    unsigned int pk[4][2];
    #pragma unroll
    for (int u = 0; u < 4; ++u) {
      const float p0 = exp2f(accS[4 * u + 0] - mn);
      const float p1 = exp2f(accS[4 * u + 1] - mn);
      const float p2 = exp2f(accS[4 * u + 2] - mn);
      const float p3 = exp2f(accS[4 * u + 3] - mn);
      lsum += (p0 + p1) + (p2 + p3);
      pk[u][0] = pkh(p0, p1);
      pk[u][1] = pkh(p2, p3);
    }
    lsum += __shfl_xor(lsum, 32);
    if (__any(up)) {  // rescale only when some lane's max advanced
      const float alpha = exp2f(m_run - mn);
      l_run = l_run * alpha + lsum;
      m_run = mn;
      #pragma unroll
      for (int mt = 0; mt < 4; ++mt)
        #pragma unroll
        for (int r = 0; r < 16; ++r) accO[mt][r] *= alpha;
    } else {
      l_run += lsum;
    }

    // ---- PV: O^T += V^T . P^T ----
    #pragma unroll
    for (int s = 0; s < 2; ++s) {
      const unsigned int s0 = pk[2 * s + (g ^ 1)][0];
      const unsigned int s1 = pk[2 * s + (g ^ 1)][1];
      const unsigned int t0 = __shfl_xor(s0, 32);
      const unsigned int t1 = __shfl_xor(s1, 32);
      union { unsigned int u[4]; h8v v; } bP;
      bP.u[0] = g ? t0 : pk[2 * s][0];
      bP.u[1] = g ? t1 : pk[2 * s][1];
      bP.u[2] = g ? pk[2 * s + 1][0] : t0;
      bP.u[3] = g ? pk[2 * s + 1][1] : t1;
      #pragma unroll
      for (int mt = 0; mt < 4; ++mt) {
        const int dr = 32 * mt + qlane;
        union { unsigned int u[4]; h8v v; } aV;
        const uint2 lo = *(const uint2*)&Vs[cur][dr * 36 + (2 * s + g) * 8];
        const uint2 hi = *(const uint2*)&Vs[cur][dr * 36 + (2 * s + g) * 8 + 4];
        aV.u[0] = lo.x; aV.u[1] = lo.y; aV.u[2] = hi.x; aV.u[3] = hi.y;
        accO[mt] = __builtin_amdgcn_mfma_f32_32x32x16_f16(aV.v, bP.v, accO[mt], 0, 0, 0);
      }
    }

    if (pre) {  // commit staged tile to the other buffer
      const int nb = cur ^ 1;
      #pragma unroll
      for (int i = 0; i < 2; ++i) {
        const int kr = (tid >> 4) + i * 16;
        *(uint4*)&Ks[nb][kr * 128 + ((tid & 15) ^ (kr & 15)) * 8] = stgK[i];
        const int idx = tid * 2 + i, dr = idx >> 2, cv = idx & 3;
        *(uint2*)&Vs[nb][dr * 36 + cv * 8]     = make_uint2(stgV[i].x, stgV[i].y);
        *(uint2*)&Vs[nb][dr * 36 + cv * 8 + 4] = make_uint2(stgV[i].z, stgV[i].w);
      }
    }
    __syncthreads();
  }

  // epilogue: unnormalized f16 partial O + per-column (m,l)
  const int ncol = n0 + 32 * wv + qlane;
  const size_t obase = (size_t)(b * KSPL + spl) * ICH * NPOS;
  #pragma unroll
  for (int mt = 0; mt < 4; ++mt)
    #pragma unroll
    for (int r = 0; r < 16; ++r) {
      const int d = 32 * mt + (r & 3) + 8 * (r >> 2) + 4 * g;
      Opart[obase + (size_t)d * NPOS + ncol] = f2h(accO[mt][r]);
    }
  if (g == 0) {
    Mpart[(size_t)(b * KSPL + spl) * NPOS + ncol] = m_run;
    Lpart[(size_t)(b * KSPL + spl) * NPOS + ncol] = l_run;
  }
}

// ---------------------------------------------------------------------------
// merge: Y^T[b][d][n] = sum_s 2^{m_s-M} O_s[d][n] / sum_s 2^{m_s-M} l_s
// ---------------------------------------------------------------------------
__global__ __launch_bounds__(256, 2)
void merge_kernel(const unsigned short* __restrict__ Opart,
                  const float* __restrict__ Mpart,
                  const float* __restrict__ Lpart,
                  float* __restrict__ Yt) {
  const int idx = blockIdx.x * 256 + threadIdx.x;   // 0 .. B*N-1
  const int b = idx / NPOS, n = idx % NPOS;
  float m[KSPL], l[KSPL], M = -1e30f;
  #pragma unroll
  for (int s = 0; s < KSPL; ++s) {
    m[s] = Mpart[(size_t)(b * KSPL + s) * NPOS + n];
    l[s] = Lpart[(size_t)(b * KSPL + s) * NPOS + n];
    M = fmaxf(M, m[s]);
  }
  float w[KSPL], ltot = 0.0f;
  #pragma unroll
  for (int s = 0; s < KSPL; ++s) { w[s] = exp2f(m[s] - M); ltot += w[s] * l[s]; }
  const float inv = 1.0f / ltot;
  for (int d = 0; d < ICH; ++d) {
    float acc = 0.0f;
    #pragma unroll
    for (int s = 0; s < KSPL; ++s) {
      const unsigned short u = Opart[((size_t)(b * KSPL + s) * ICH + d) * NPOS + n];
      acc += w[s] * (float)__builtin_bit_cast(_Float16, u);
    }
    Yt[((size_t)b * ICH + d) * NPOS + n] = acc * inv;
  }
}

// ---------------------------------------------------------------------------
// zres: out[b][c][n] = sum_ic Wz[c][ic] * Y^T[b][ic][n] + x  (b128 LDS)
// ---------------------------------------------------------------------------
__global__ __launch_bounds__(256, 2)
void zres_kernel(const float* __restrict__ x,
                 const float* __restrict__ Wz,
                 const float* __restrict__ Yt,
                 float* __restrict__ out) {
  const int n0 = blockIdx.x * 64;
  const int c0 = blockIdx.y * 64;
  const int b  = blockIdx.z;
  __shared__ float Yts[16][68];   // [k(ic)][n]
  __shared__ float Wzt[16][68];   // [k][c]
  const int tid = threadIdx.x;
  const int tx = tid & 15, ty = tid >> 4;
  float acc[4][4] = {};           // rows c = ty*4+i, cols n = tx*4+j

  for (int ic0 = 0; ic0 < ICH; ic0 += 16) {
    {
      const int nn = tid & 63, k4 = tid >> 6;
      #pragma unroll
      for (int q = 0; q < 4; ++q) {
        const int kk = k4 + q * 4;
        Yts[kk][nn] = Yt[((size_t)b * ICH + ic0 + kk) * NPOS + n0 + nn];
      }
      const int wk = tid & 15, wo = tid >> 4;
      #pragma unroll
      for (int q = 0; q < 4; ++q) {
        const int cc = wo + q * 16;
        Wzt[wk][cc] = Wz[(size_t)(c0 + cc) * ICH + ic0 + wk];
      }
    }
    __syncthreads();
    #pragma unroll
    for (int kk = 0; kk < 16; ++kk) {
      const float4 av = *(const float4*)&Wzt[kk][ty * 4];
      const float4 bv = *(const float4*)&Yts[kk][tx * 4];
      const float a_[4] = {av.x, av.y, av.z, av.w};
      const float b_[4] = {bv.x, bv.y, bv.z, bv.w};
      #pragma unroll
      for (int i = 0; i < 4; ++i)
        #pragma unroll
        for (int j = 0; j < 4; ++j) acc[i][j] += a_[i] * b_[j];
    }
    __syncthreads();
  }
  #pragma unroll
  for (int i = 0; i < 4; ++i) {
    const size_t base = ((size_t)(b * CCH + c0 + ty * 4 + i)) * NPOS + n0 + tx * 4;
    const float4 xr = *(const float4*)&x[base];
    float4 v;
    v.x = acc[i][0] + xr.x; v.y = acc[i][1] + xr.y;
    v.z = acc[i][2] + xr.z; v.w = acc[i][3] + xr.w;
    *(float4*)&out[base] = v;
  }
}

// ---------------------------------------------------------------------------
extern "C" void kernel_launch(void* const* d_in, const int* in_sizes, int n_in,
                              void* d_out, int out_size, void* d_ws, size_t ws_size,
                              hipStream_t stream) {
  const float* x      = (const float*)d_in[0];
  const float* Wg     = (const float*)d_in[1];
  const float* Wtheta = (const float*)d_in[2];
  const float* Wphi   = (const float*)d_in[3];
  const float* Wz     = (const float*)d_in[4];
  float* out = (float*)d_out;

  unsigned short* Qg    = (unsigned short*)d_ws;
  unsigned short* Kg    = Qg + BNIC;
  unsigned short* Vtg   = Kg + BNIC;
  unsigned short* Opart = Vtg + BNIC;                    // KSPL*BNIC ushorts
  float* Mpart = (float*)(Opart + (size_t)KSPL * BNIC);  // KSPL*B*N floats
  float* Lpart = Mpart + (size_t)KSPL * BB * NPOS;       // KSPL*B*N floats
  float* Yt    = (float*)Qg;                             // overlay after flash4

  proj_qk<<<dim3(NPOS / 64, 4, BB), 256, 0, stream>>>(x, Wtheta, Wphi, Qg, Kg);
  proj_v <<<dim3(NPOS / 64, 2, BB), 256, 0, stream>>>(x, Wg, Vtg);
  flash4 <<<dim3(NPOS / 128, KSPL, BB), 256, 0, stream>>>(Qg, Kg, Vtg, Opart, Mpart, Lpart);
  merge_kernel<<<dim3(BB * NPOS / 256), 256, 0, stream>>>(Opart, Mpart, Lpart, Yt);
  zres_kernel<<<dim3(NPOS / 64, CCH / 64, BB), 256, 0, stream>>>(x, Wz, Yt, out);
}

// Round 8
// 385.671 us; speedup vs baseline: 1.5308x; 1.0641x over previous
//
#include <hip/hip_runtime.h>
#include <cstdint>

// SpacetimeNonLocalBlock: B=4, C=256, T*H*W=N=6272, IC=128.
// R7: (1) flash5 = flash4 + slack-fold softmax (fold only when max advances by
// >12 log2 units; epilogue renormalizes to true max — exact math, kills the
// per-iter 64-mul accO rescale that made flash4 VALU-bound at 42% VALUBusy).
// (2) proj_qkv: single fused projection kernel, x staged once per c-chunk for
// all 6 weight tiles (LDS instr/FMA -45%, x HBM reads 154->26 MB).
// (3) zres 8x8 thread-tile (1B/FMA LDS), merge 2n-vectorized.
// ws layout unchanged: Qg|Kg|Vtg f16 | Opart f16 KSPL*BNIC | Mpart,Lpart f32.

#define BB   4
#define CCH  256
#define NPOS 6272
#define ICH  128
#define BNIC ((size_t)BB * NPOS * ICH)
#define KSPL 4
#define KLEN (NPOS / KSPL)   // 1568
#define TKF  32
#define NITK (KLEN / TKF)    // 49
#define SLACK 12.0f

typedef __attribute__((ext_vector_type(8)))  _Float16 h8v;  // 8 f16 MFMA frag
typedef __attribute__((ext_vector_type(16))) float fx16;    // 32x32 acc

__device__ __forceinline__ unsigned short f2h(float f) {
  _Float16 h = (_Float16)f;
  return __builtin_bit_cast(unsigned short, h);
}
__device__ __forceinline__ unsigned int pkh(float lo, float hi) {
  return __builtin_bit_cast(unsigned int, __builtin_amdgcn_cvt_pkrtz(lo, hi));
}

// ---------------------------------------------------------------------------
// proj_qkv: fused Q/K/V projections. grid (N/64, B); block 256.
// Q,K -> [b][n][128] f16 (Q pre-scaled log2e); V -> V^T [b][128][N] f16.
// LDS 30.5 KB: Xt[16][68] + Wt[6][16][68]. Inner: 1 av + 6 bv b128 per kk.
// ---------------------------------------------------------------------------
__global__ __launch_bounds__(256, 1)
void proj_qkv(const float* __restrict__ x,
              const float* __restrict__ Wtheta,
              const float* __restrict__ Wphi,
              const float* __restrict__ Wg,
              unsigned short* __restrict__ Qg,
              unsigned short* __restrict__ Kg,
              unsigned short* __restrict__ Vtg) {
  const int n0 = blockIdx.x * 64;
  const int b  = blockIdx.y;
  __shared__ float Xt[16][68];      // [k][n]
  __shared__ float Wt[6][16][68];   // [tile][k][o]
  const int tid = threadIdx.x;
  const int tx = tid & 15, ty = tid >> 4;
  float acc[6][4][4] = {};          // [tile][n_i][o_j]
  const float* Ws[3] = {Wtheta, Wphi, Wg};

  for (int c0 = 0; c0 < CCH; c0 += 16) {
    {
      const int nn = tid & 63, k4 = tid >> 6;
      #pragma unroll
      for (int q = 0; q < 4; ++q) {
        const int kk = k4 + q * 4;
        Xt[kk][nn] = x[((size_t)(b * CCH + c0 + kk)) * NPOS + n0 + nn];
      }
      const int wk = tid & 15, wo = tid >> 4;
      #pragma unroll
      for (int w = 0; w < 6; ++w) {
        const float* W = Ws[w >> 1];
        const int o_half = (w & 1) * 64;
        #pragma unroll
        for (int q = 0; q < 4; ++q) {
          const int oo = wo + q * 16;
          Wt[w][wk][oo] = W[(size_t)(o_half + oo) * CCH + c0 + wk];
        }
      }
    }
    __syncthreads();
    #pragma unroll
    for (int kk = 0; kk < 16; ++kk) {
      const float4 av = *(const float4*)&Xt[kk][ty * 4];
      const float a_[4] = {av.x, av.y, av.z, av.w};
      #pragma unroll
      for (int w = 0; w < 6; ++w) {
        const float4 bv = *(const float4*)&Wt[w][kk][tx * 4];
        const float b_[4] = {bv.x, bv.y, bv.z, bv.w};
        #pragma unroll
        for (int i = 0; i < 4; ++i)
          #pragma unroll
          for (int j = 0; j < 4; ++j) acc[w][i][j] += a_[i] * b_[j];
      }
    }
    __syncthreads();
  }

  const float LOG2E = 1.4426950408889634f;
  // Q (tiles 0,1) and K (tiles 2,3): [n][o] rows
  #pragma unroll
  for (int w = 0; w < 4; ++w) {
    const int o_half = (w & 1) * 64;
    unsigned short* Out = (w < 2) ? Qg : Kg;
    const float scl = (w < 2) ? LOG2E : 1.0f;
    #pragma unroll
    for (int i = 0; i < 4; ++i) {
      ushort4 v;
      v.x = f2h(acc[w][i][0] * scl); v.y = f2h(acc[w][i][1] * scl);
      v.z = f2h(acc[w][i][2] * scl); v.w = f2h(acc[w][i][3] * scl);
      *(ushort4*)&Out[((size_t)b * NPOS + n0 + ty * 4 + i) * ICH + o_half + tx * 4] = v;
    }
  }
  // V (tiles 4,5): V^T[o][n] — transpose in-register (i<->j roles)
  #pragma unroll
  for (int w = 4; w < 6; ++w) {
    const int o_half = (w & 1) * 64;
    #pragma unroll
    for (int j = 0; j < 4; ++j) {
      const int o = o_half + tx * 4 + j;
      ushort4 v;
      v.x = f2h(acc[w][0][j]); v.y = f2h(acc[w][1][j]);
      v.z = f2h(acc[w][2][j]); v.w = f2h(acc[w][3][j]);
      *(ushort4*)&Vtg[((size_t)b * ICH + o) * NPOS + n0 + ty * 4] = v;
    }
  }
}

// ---------------------------------------------------------------------------
// flash5: grid (49, KSPL, B), 4 waves, q=32/wave, TK=32. Slack-fold softmax:
// fold accO only when max advances by >SLACK; epilogue renorms to true max.
// LDS 34 KB: Ks[2][32x128] 4-bit swz, Vs[2][128x36].
// ---------------------------------------------------------------------------
__global__ __launch_bounds__(256, 2)
void flash5(const unsigned short* __restrict__ Qg,
            const unsigned short* __restrict__ Kg,
            const unsigned short* __restrict__ Vtg,
            unsigned short* __restrict__ Opart,
            float* __restrict__ Mpart,
            float* __restrict__ Lpart) {
  __shared__ unsigned short Ks[2][TKF * 128];
  __shared__ unsigned short Vs[2][128 * 36];

  const int b   = blockIdx.z;
  const int spl = blockIdx.y;
  const int n0  = blockIdx.x * 128;
  const int kb  = spl * KLEN;
  const int tid = threadIdx.x;
  const int lane = tid & 63, wv = tid >> 6;
  const int qlane = lane & 31, g = lane >> 5;
  const int swz = qlane & 15;

  h8v qf[8];
  {
    const size_t qbase = ((size_t)b * NPOS + n0 + 32 * wv + qlane) * ICH;
    #pragma unroll
    for (int cs = 0; cs < 8; ++cs)
      qf[cs] = *(const h8v*)&Qg[qbase + cs * 16 + g * 8];
  }

  {
    #pragma unroll
    for (int i = 0; i < 2; ++i) {
      const int kr = (tid >> 4) + i * 16, c = tid & 15;
      const uint4 v = *(const uint4*)&Kg[((size_t)b * NPOS + kb + kr) * ICH + c * 8];
      *(uint4*)&Ks[0][kr * 128 + (c ^ (kr & 15)) * 8] = v;
      const int idx = tid * 2 + i, dr = idx >> 2, cv = idx & 3;
      const uint4 w = *(const uint4*)&Vtg[((size_t)b * ICH + dr) * NPOS + kb + cv * 8];
      *(uint2*)&Vs[0][dr * 36 + cv * 8]     = make_uint2(w.x, w.y);
      *(uint2*)&Vs[0][dr * 36 + cv * 8 + 4] = make_uint2(w.z, w.w);
    }
  }
  __syncthreads();

  float m_run = -1e30f, m_true = -1e30f, l_run = 0.0f;
  fx16 accO[4];
  #pragma unroll
  for (int mt = 0; mt < 4; ++mt) accO[mt] = (fx16)(0.0f);

  uint4 stgK[2], stgV[2];

  for (int it = 0; it < NITK; ++it) {
    const int cur = it & 1;
    const bool pre = (it + 1 < NITK);
    if (pre) {
      const int k0n = kb + (it + 1) * TKF;
      #pragma unroll
      for (int i = 0; i < 2; ++i) {
        const int kr = (tid >> 4) + i * 16;
        stgK[i] = *(const uint4*)&Kg[((size_t)b * NPOS + k0n + kr) * ICH + (tid & 15) * 8];
        const int idx = tid * 2 + i, dr = idx >> 2, cv = idx & 3;
        stgV[i] = *(const uint4*)&Vtg[((size_t)b * ICH + dr) * NPOS + k0n + cv * 8];
      }
    }

    // ---- S^T = K . Q^T ----
    fx16 accS = (fx16)(0.0f);
    #pragma unroll
    for (int cs = 0; cs < 8; ++cs) {
      const h8v aK = *(const h8v*)&Ks[cur][qlane * 128 + ((2 * cs + g) ^ swz) * 8];
      accS = __builtin_amdgcn_mfma_f32_32x32x16_f16(aK, qf[cs], accS, 0, 0, 0);
    }

    // ---- slack-fold online softmax (log2 domain) ----
    float mx = accS[0];
    #pragma unroll
    for (int r = 1; r < 16; ++r) mx = fmaxf(mx, accS[r]);
    mx = fmaxf(mx, __shfl_xor(mx, 32));
    m_true = fmaxf(m_true, mx);
    const bool fold = __any(mx > m_run + SLACK);
    const float mn = fold ? fmaxf(m_run, mx) : m_run;
    float lsum = 0.0f;
    unsigned int pk[4][2];
    #pragma unroll
    for (int u = 0; u < 4; ++u) {
      const float p0 = exp2f(accS[4 * u + 0] - mn);
      const float p1 = exp2f(accS[4 * u + 1] - mn);
      const float p2 = exp2f(accS[4 * u + 2] - mn);
      const float p3 = exp2f(accS[4 * u + 3] - mn);
      lsum += (p0 + p1) + (p2 + p3);
      pk[u][0] = pkh(p0, p1);
      pk[u][1] = pkh(p2, p3);
    }
    lsum += __shfl_xor(lsum, 32);
    if (fold) {
      const float alpha = exp2f(m_run - mn);
      l_run = l_run * alpha + lsum;
      m_run = mn;
      #pragma unroll
      for (int mt = 0; mt < 4; ++mt)
        #pragma unroll
        for (int r = 0; r < 16; ++r) accO[mt][r] *= alpha;
    } else {
      l_run += lsum;
    }

    // ---- PV: O^T += V^T . P^T ----
    #pragma unroll
    for (int s = 0; s < 2; ++s) {
      const unsigned int s0 = pk[2 * s + (g ^ 1)][0];
      const unsigned int s1 = pk[2 * s + (g ^ 1)][1];
      const unsigned int t0 = __shfl_xor(s0, 32);
      const unsigned int t1 = __shfl_xor(s1, 32);
      union { unsigned int u[4]; h8v v; } bP;
      bP.u[0] = g ? t0 : pk[2 * s][0];
      bP.u[1] = g ? t1 : pk[2 * s][1];
      bP.u[2] = g ? pk[2 * s + 1][0] : t0;
      bP.u[3] = g ? pk[2 * s + 1][1] : t1;
      #pragma unroll
      for (int mt = 0; mt < 4; ++mt) {
        const int dr = 32 * mt + qlane;
        union { unsigned int u[4]; h8v v; } aV;
        const uint2 lo = *(const uint2*)&Vs[cur][dr * 36 + (2 * s + g) * 8];
        const uint2 hi = *(const uint2*)&Vs[cur][dr * 36 + (2 * s + g) * 8 + 4];
        aV.u[0] = lo.x; aV.u[1] = lo.y; aV.u[2] = hi.x; aV.u[3] = hi.y;
        accO[mt] = __builtin_amdgcn_mfma_f32_32x32x16_f16(aV.v, bP.v, accO[mt], 0, 0, 0);
      }
    }

    if (pre) {
      const int nb = cur ^ 1;
      #pragma unroll
      for (int i = 0; i < 2; ++i) {
        const int kr = (tid >> 4) + i * 16;
        *(uint4*)&Ks[nb][kr * 128 + ((tid & 15) ^ (kr & 15)) * 8] = stgK[i];
        const int idx = tid * 2 + i, dr = idx >> 2, cv = idx & 3;
        *(uint2*)&Vs[nb][dr * 36 + cv * 8]     = make_uint2(stgV[i].x, stgV[i].y);
        *(uint2*)&Vs[nb][dr * 36 + cv * 8 + 4] = make_uint2(stgV[i].z, stgV[i].w);
      }
    }
    __syncthreads();
  }

  // epilogue: renormalize to true max, store f16 partial O + (m,l)
  const float scale = exp2f(m_run - m_true);
  const int ncol = n0 + 32 * wv + qlane;
  const size_t obase = (size_t)(b * KSPL + spl) * ICH * NPOS;
  #pragma unroll
  for (int mt = 0; mt < 4; ++mt)
    #pragma unroll
    for (int r = 0; r < 16; ++r) {
      const int d = 32 * mt + (r & 3) + 8 * (r >> 2) + 4 * g;
      Opart[obase + (size_t)d * NPOS + ncol] = f2h(accO[mt][r] * scale);
    }
  if (g == 0) {
    Mpart[(size_t)(b * KSPL + spl) * NPOS + ncol] = m_true;
    Lpart[(size_t)(b * KSPL + spl) * NPOS + ncol] = l_run * scale;
  }
}

// ---------------------------------------------------------------------------
// merge (2n per thread): Y^T[b][d][n] = sum_s 2^{m_s-M} O_s / sum_s 2^{m_s-M} l_s
// ---------------------------------------------------------------------------
__global__ __launch_bounds__(256, 2)
void merge_kernel(const unsigned short* __restrict__ Opart,
                  const float* __restrict__ Mpart,
                  const float* __restrict__ Lpart,
                  float* __restrict__ Yt) {
  const int idx = (blockIdx.x * 256 + threadIdx.x) * 2;   // 0 .. B*N-1 step 2
  const int b = idx / NPOS, n = idx % NPOS;
  float m[KSPL][2], l[KSPL][2], M0 = -1e30f, M1 = -1e30f;
  #pragma unroll
  for (int s = 0; s < KSPL; ++s) {
    const size_t base = (size_t)(b * KSPL + s) * NPOS + n;
    m[s][0] = Mpart[base]; m[s][1] = Mpart[base + 1];
    l[s][0] = Lpart[base]; l[s][1] = Lpart[base + 1];
    M0 = fmaxf(M0, m[s][0]); M1 = fmaxf(M1, m[s][1]);
  }
  float w[KSPL][2], lt0 = 0.0f, lt1 = 0.0f;
  #pragma unroll
  for (int s = 0; s < KSPL; ++s) {
    w[s][0] = exp2f(m[s][0] - M0); lt0 += w[s][0] * l[s][0];
    w[s][1] = exp2f(m[s][1] - M1); lt1 += w[s][1] * l[s][1];
  }
  const float inv0 = 1.0f / lt0, inv1 = 1.0f / lt1;
  for (int d = 0; d < ICH; ++d) {
    float a0 = 0.0f, a1 = 0.0f;
    #pragma unroll
    for (int s = 0; s < KSPL; ++s) {
      const unsigned int u = *(const unsigned int*)
        &Opart[((size_t)(b * KSPL + s) * ICH + d) * NPOS + n];
      a0 += w[s][0] * (float)__builtin_bit_cast(_Float16, (unsigned short)(u & 0xffff));
      a1 += w[s][1] * (float)__builtin_bit_cast(_Float16, (unsigned short)(u >> 16));
    }
    float2 o; o.x = a0 * inv0; o.y = a1 * inv1;
    *(float2*)&Yt[((size_t)b * ICH + d) * NPOS + n] = o;
  }
}

// ---------------------------------------------------------------------------
// zres: out[b][c][n] = sum_ic Wz[c][ic]*Y^T[b][ic][n] + x. 128x128 block,
// 8x8 thread tile via wave quadrants (both LDS operand reads <=2-way).
// ---------------------------------------------------------------------------
__global__ __launch_bounds__(256, 2)
void zres_kernel(const float* __restrict__ x,
                 const float* __restrict__ Wz,
                 const float* __restrict__ Yt,
                 float* __restrict__ out) {
  const int n0 = blockIdx.x * 128;
  const int c0 = blockIdx.y * 128;
  const int b  = blockIdx.z;
  __shared__ float Yts[16][128];   // [k(ic)][n]
  __shared__ float Wzt[16][128];   // [k][c]
  const int tid = threadIdx.x;
  const int lane = tid & 63, wv = tid >> 6;
  const int tn = lane & 7, tc = lane >> 3;           // 8x8 within wave
  const int nb = (wv & 1) * 64 + tn * 8;             // n offset in block
  const int cb = (wv >> 1) * 64 + tc * 8;            // c offset in block
  float acc[8][8] = {};                              // [c_i][n_j]

  for (int ic0 = 0; ic0 < ICH; ic0 += 16) {
    {
      const int nn = tid & 127, kh = tid >> 7;
      #pragma unroll
      for (int q = 0; q < 8; ++q) {
        const int kk = kh + q * 2;
        Yts[kk][nn] = Yt[((size_t)b * ICH + ic0 + kk) * NPOS + n0 + nn];
      }
      const int wk = tid & 15, wo = tid >> 4;
      #pragma unroll
      for (int q = 0; q < 8; ++q) {
        const int cc = wo + q * 16;
        Wzt[wk][cc] = Wz[(size_t)(c0 + cc) * ICH + ic0 + wk];
      }
    }
    __syncthreads();
    #pragma unroll
    for (int kk = 0; kk < 16; ++kk) {
      const float4 a0 = *(const float4*)&Wzt[kk][cb];
      const float4 a1 = *(const float4*)&Wzt[kk][cb + 4];
      const float4 b0 = *(const float4*)&Yts[kk][nb];
      const float4 b1 = *(const float4*)&Yts[kk][nb + 4];
      const float a_[8] = {a0.x, a0.y, a0.z, a0.w, a1.x, a1.y, a1.z, a1.w};
      const float b_[8] = {b0.x, b0.y, b0.z, b0.w, b1.x, b1.y, b1.z, b1.w};
      #pragma unroll
      for (int i = 0; i < 8; ++i)
        #pragma unroll
        for (int j = 0; j < 8; ++j) acc[i][j] += a_[i] * b_[j];
    }
    __syncthreads();
  }
  #pragma unroll
  for (int i = 0; i < 8; ++i) {
    const size_t base = ((size_t)(b * CCH + c0 + cb + i)) * NPOS + n0 + nb;
    const float4 x0 = *(const float4*)&x[base];
    const float4 x1 = *(const float4*)&x[base + 4];
    float4 v0, v1;
    v0.x = acc[i][0] + x0.x; v0.y = acc[i][1] + x0.y;
    v0.z = acc[i][2] + x0.z; v0.w = acc[i][3] + x0.w;
    v1.x = acc[i][4] + x1.x; v1.y = acc[i][5] + x1.y;
    v1.z = acc[i][6] + x1.z; v1.w = acc[i][7] + x1.w;
    *(float4*)&out[base]     = v0;
    *(float4*)&out[base + 4] = v1;
  }
}

// ---------------------------------------------------------------------------
extern "C" void kernel_launch(void* const* d_in, const int* in_sizes, int n_in,
                              void* d_out, int out_size, void* d_ws, size_t ws_size,
                              hipStream_t stream) {
  const float* x      = (const float*)d_in[0];
  const float* Wg     = (const float*)d_in[1];
  const float* Wtheta = (const float*)d_in[2];
  const float* Wphi   = (const float*)d_in[3];
  const float* Wz     = (const float*)d_in[4];
  float* out = (float*)d_out;

  unsigned short* Qg    = (unsigned short*)d_ws;
  unsigned short* Kg    = Qg + BNIC;
  unsigned short* Vtg   = Kg + BNIC;
  unsigned short* Opart = Vtg + BNIC;                    // KSPL*BNIC ushorts
  float* Mpart = (float*)(Opart + (size_t)KSPL * BNIC);  // KSPL*B*N floats
  float* Lpart = Mpart + (size_t)KSPL * BB * NPOS;       // KSPL*B*N floats
  float* Yt    = (float*)Qg;                             // overlay after flash5

  proj_qkv<<<dim3(NPOS / 64, BB), 256, 0, stream>>>(x, Wtheta, Wphi, Wg, Qg, Kg, Vtg);
  flash5  <<<dim3(NPOS / 128, KSPL, BB), 256, 0, stream>>>(Qg, Kg, Vtg, Opart, Mpart, Lpart);
  merge_kernel<<<dim3(BB * NPOS / 512), 256, 0, stream>>>(Opart, Mpart, Lpart, Yt);
  zres_kernel<<<dim3(NPOS / 128, CCH / 128, BB), 256, 0, stream>>>(x, Wz, Yt, out);
}